// Round 1
// baseline (260.288 us; speedup 1.0000x reference)
//
#include <hip/hip_runtime.h>
#include <math.h>

#define LOOKBACK 336
#define NFEAT    164
#define HORIZON  96
#define DMODEL   64
#define DSTATE   16
#define DCONV    4
#define DINNER   128
#define DTRANK   4
#define MLPH     64
#define BATCH    512
#define TC       48      // timesteps per chunk; 7*48 = 336
#define NCHUNK   7
#define XCP      132     // padded row stride for xc_s/delta_s (breaks 128-stride bank aliasing)

__device__ __forceinline__ float silu_f(float x) {
    return x / (1.f + __expf(-x));
}
__device__ __forceinline__ float softplus_f(float x) {
    return (x > 15.f) ? x : __logf(1.f + __expf(x));
}

__global__ __launch_bounds__(256, 2) void mamba_fused(
    const float* __restrict__ x_raw,      // (512,336)
    const float* __restrict__ x_features, // (512,164)
    const float* __restrict__ embed_W,    // (1,64)
    const float* __restrict__ embed_b,    // (64)
    const float* __restrict__ in_W,       // (64,256)
    const float* __restrict__ conv_W,     // (128,4)
    const float* __restrict__ conv_b,     // (128)
    const float* __restrict__ xproj_W,    // (128,36)
    const float* __restrict__ dt_W,       // (4,128)
    const float* __restrict__ dt_b,       // (128)
    const float* __restrict__ A_log,      // (128,16)
    const float* __restrict__ Dvec,       // (128)
    const float* __restrict__ out_W,      // (128,64)
    const float* __restrict__ mlp_W1,     // (164,64)
    const float* __restrict__ mlp_b1,     // (64)
    const float* __restrict__ mlp_W2,     // (64,32)
    const float* __restrict__ mlp_b2,     // (32)
    const float* __restrict__ head_W,     // (96,96)
    const float* __restrict__ head_b,     // (96)
    float* __restrict__ out)              // (512,96)
{
    __shared__ float xr[LOOKBACK];
    __shared__ float w1s[2*DINNER];
    __shared__ float w0s[2*DINNER];
    __shared__ float xprojT[20][DINNER];   // transposed cols 0..19 (dt:0..3, B:4..19)
    __shared__ float dtWs[DTRANK][DINNER];
    __shared__ float dtbs[DINNER];
    __shared__ float xc_s[TC][XCP];        // conv+silu output, later u = delta*xc (in place)
    __shared__ float delta_s[TC][XCP];
    __shared__ float Bs[TC][DSTATE];
    __shared__ float dtraw[TC][DTRANK];
    __shared__ float xc_last[DINNER];
    __shared__ float zsil[DINNER];
    __shared__ float Cl[DSTATE];
    __shared__ float yv[DINNER];
    __shared__ float hfin[96];             // [0..63] mamba out, [64..95] mlp out
    __shared__ float mlph[MLPH];

    const int tid = threadIdx.x;
    const int b   = blockIdx.x;

    // ---------------- prologue loads ----------------
    for (int i = tid; i < LOOKBACK; i += 256) xr[i] = x_raw[b*LOOKBACK + i];

    {   // w1/w0: rank-1 embed folded through in_W; j = tid in 0..255
        float a1 = 0.f, a0 = 0.f;
        for (int dm = 0; dm < DMODEL; ++dm) {
            float w = in_W[dm*(2*DINNER) + tid];
            a1 += embed_W[dm] * w;
            a0 += embed_b[dm] * w;
        }
        w1s[tid] = a1; w0s[tid] = a0;
    }
    for (int idx = tid; idx < 20*DINNER; idx += 256) {
        int jj = idx >> 7, d = idx & 127;
        xprojT[jj][d] = xproj_W[d*36 + jj];
    }
    for (int idx = tid; idx < DTRANK*DINNER; idx += 256) {
        dtWs[idx >> 7][idx & 127] = dt_W[idx];
    }
    if (tid < DINNER) dtbs[tid] = dt_b[tid];

    // MLP stage 1 (independent branch)
    if (tid < MLPH) {
        float acc = mlp_b1[tid];
        const float* xf = x_features + b*NFEAT;
        for (int f = 0; f < NFEAT; ++f) acc += xf[f]*mlp_W1[f*MLPH + tid];
        mlph[tid] = fmaxf(acc, 0.f);
    }
    __syncthreads();

    // per-thread constants
    const int dA1 = tid & 127;          // channel for phases A1/A3
    const float w1d = w1s[dA1], w0d = w0s[dA1];
    const float cw0 = conv_W[dA1*4+0], cw1 = conv_W[dA1*4+1],
                cw2 = conv_W[dA1*4+2], cw3 = conv_W[dA1*4+3];
    const float cb  = conv_b[dA1];

    // phase-B state: d = tid>>1, states n0..n0+7
    const int dB = tid >> 1;
    const int n0 = (tid & 1) * 8;
    float Areg[8], h[8];
    #pragma unroll
    for (int i = 0; i < 8; ++i) {
        Areg[i] = -__expf(A_log[dB*DSTATE + n0 + i]);
        h[i] = 0.f;
    }

    // MLP stage 2 (after barrier covering mlph)
    if (tid < 32) {
        float acc = mlp_b2[tid];
        for (int k = 0; k < MLPH; ++k) acc += mlph[k]*mlp_W2[k*32 + tid];
        hfin[64 + tid] = acc;
    }

    // ---------------- chunked main loop ----------------
    for (int c = 0; c < NCHUNK; ++c) {
        const int tbase = c * TC;

        // A1: depthwise causal conv4 + silu. (tt,d) grid, d fixed per thread.
        #pragma unroll 4
        for (int ii = 0; ii < TC/2; ++ii) {
            int tt = (tid >> 7) + 2*ii;
            int t  = tbase + tt;
            float acc = cb;
            int t0 = t - 3;
            if (t0 >= 0)     acc += (xr[t0  ]*w1d + w0d) * cw0;
            if (t0 + 1 >= 0) acc += (xr[t0+1]*w1d + w0d) * cw1;
            if (t0 + 2 >= 0) acc += (xr[t0+2]*w1d + w0d) * cw2;
            acc += (xr[t]*w1d + w0d) * cw3;   // k=3 always valid (t>=0)
            float v = silu_f(acc);
            xc_s[tt][dA1] = v;
            if (t == LOOKBACK-1) xc_last[dA1] = v;
        }
        __syncthreads();

        // A2: [TC x 128] @ [128 x 20] -> dt(4) + B(16). 2x2 register tiles.
        if (tid < 240) {
            const int ttp = tid / 10;           // 0..23  (t pair)
            const int tjp = tid - ttp*10;       // 0..9   (j pair)
            const int t0 = ttp*2, j0 = tjp*2;
            float a00=0.f, a01=0.f, a10=0.f, a11=0.f;
            const float* xc0 = &xc_s[t0][0];
            const float* xc1 = &xc_s[t0+1][0];
            const float* p0  = &xprojT[j0][0];
            const float* p1  = &xprojT[j0+1][0];
            #pragma unroll 4
            for (int d = 0; d < DINNER; d += 4) {
                float4 x0 = *(const float4*)(xc0 + d);
                float4 x1 = *(const float4*)(xc1 + d);
                float4 q0 = *(const float4*)(p0 + d);
                float4 q1 = *(const float4*)(p1 + d);
                a00 += x0.x*q0.x + x0.y*q0.y + x0.z*q0.z + x0.w*q0.w;
                a01 += x0.x*q1.x + x0.y*q1.y + x0.z*q1.z + x0.w*q1.w;
                a10 += x1.x*q0.x + x1.y*q0.y + x1.z*q0.z + x1.w*q0.w;
                a11 += x1.x*q1.x + x1.y*q1.y + x1.z*q1.z + x1.w*q1.w;
            }
            if (j0 < 4) {
                dtraw[t0  ][j0  ] = a00;
                dtraw[t0  ][j0+1] = a01;
                dtraw[t0+1][j0  ] = a10;
                dtraw[t0+1][j0+1] = a11;
            } else {
                Bs[t0  ][j0-4] = a00;
                Bs[t0  ][j0-3] = a01;
                Bs[t0+1][j0-4] = a10;
                Bs[t0+1][j0-3] = a11;
            }
        }
        __syncthreads();

        // A3: delta = softplus(dt@dt_W + dt_b); u = delta*xc in place
        #pragma unroll 4
        for (int ii = 0; ii < TC/2; ++ii) {
            int tt = (tid >> 7) + 2*ii;
            float r0 = dtraw[tt][0], r1 = dtraw[tt][1],
                  r2 = dtraw[tt][2], r3 = dtraw[tt][3];
            float acc = dtbs[dA1] + r0*dtWs[0][dA1] + r1*dtWs[1][dA1]
                                  + r2*dtWs[2][dA1] + r3*dtWs[3][dA1];
            float dl = softplus_f(acc);
            delta_s[tt][dA1] = dl;
            xc_s[tt][dA1] *= dl;
        }
        __syncthreads();

        // B: sequential scan over the chunk; 8 states/thread in registers
        #pragma unroll 2
        for (int tt = 0; tt < TC; ++tt) {
            float dl = delta_s[tt][dB];
            float ux = xc_s[tt][dB];
            const float* Brow = &Bs[tt][0];
            float4 b0 = *(const float4*)(Brow + n0);
            float4 b1 = *(const float4*)(Brow + n0 + 4);
            h[0] = __expf(dl*Areg[0])*h[0] + ux*b0.x;
            h[1] = __expf(dl*Areg[1])*h[1] + ux*b0.y;
            h[2] = __expf(dl*Areg[2])*h[2] + ux*b0.z;
            h[3] = __expf(dl*Areg[3])*h[3] + ux*b0.w;
            h[4] = __expf(dl*Areg[4])*h[4] + ux*b1.x;
            h[5] = __expf(dl*Areg[5])*h[5] + ux*b1.y;
            h[6] = __expf(dl*Areg[6])*h[6] + ux*b1.z;
            h[7] = __expf(dl*Areg[7])*h[7] + ux*b1.w;
        }
        __syncthreads();
    }

    // ---------------- epilogue (last timestep only) ----------------
    if (tid < DINNER) {  // z-gate at t=335: z = xz[:,128+d]
        float zv = xr[LOOKBACK-1]*w1s[DINNER+tid] + w0s[DINNER+tid];
        zsil[tid] = silu_f(zv);
    }
    if (tid < DSTATE) {  // C at t=335
        float acc = 0.f;
        for (int d = 0; d < DINNER; ++d) acc += xc_last[d]*xproj_W[d*36 + 20 + tid];
        Cl[tid] = acc;
    }
    __syncthreads();

    {   // y[d] = h[d,:]·C + xc_last[d]*D[d], gated by silu(z)
        float part = 0.f;
        #pragma unroll
        for (int i = 0; i < 8; ++i) part += h[i]*Cl[n0 + i];
        float other = __shfl_xor(part, 1);
        if ((tid & 1) == 0) {
            float y = part + other + xc_last[dB]*Dvec[dB];
            yv[dB] = y * zsil[dB];
        }
    }
    __syncthreads();

    if (tid < DMODEL) {  // mamba out projection (last timestep only)
        float acc = 0.f;
        for (int d = 0; d < DINNER; ++d) acc += yv[d]*out_W[d*DMODEL + tid];
        hfin[tid] = acc;
    }
    __syncthreads();

    if (tid < HORIZON) { // head: concat(mamba, mlp) @ head_W + head_b
        float acc = head_b[tid];
        for (int i = 0; i < 96; ++i) acc += hfin[i]*head_W[i*HORIZON + tid];
        out[b*HORIZON + tid] = acc;
    }
}

extern "C" void kernel_launch(void* const* d_in, const int* in_sizes, int n_in,
                              void* d_out, int out_size, void* d_ws, size_t ws_size,
                              hipStream_t stream) {
    (void)in_sizes; (void)n_in; (void)d_ws; (void)ws_size; (void)out_size;
    mamba_fused<<<BATCH, 256, 0, stream>>>(
        (const float*)d_in[0],  (const float*)d_in[1],  (const float*)d_in[2],
        (const float*)d_in[3],  (const float*)d_in[4],  (const float*)d_in[5],
        (const float*)d_in[6],  (const float*)d_in[7],  (const float*)d_in[8],
        (const float*)d_in[9],  (const float*)d_in[10], (const float*)d_in[11],
        (const float*)d_in[12], (const float*)d_in[13], (const float*)d_in[14],
        (const float*)d_in[15], (const float*)d_in[16], (const float*)d_in[17],
        (const float*)d_in[18], (float*)d_out);
}